// Round 8
// baseline (474.659 us; speedup 1.0000x reference)
//
#include <hip/hip_runtime.h>
#include <hip/hip_cooperative_groups.h>
#include <math.h>

namespace cg = cooperative_groups;

constexpr int Bc = 2, Lc = 256, DMc = 256, Hc = 8, DHc = 32;
constexpr float LOG2E = 1.4426950408889634f;
constexpr float NEGC  = -0.72134752044448f;       // -log2e/2
constexpr float RSQRT_DH = 0.17677669529663687f;  // 1/sqrt(32)
#define EXP2 __builtin_amdgcn_exp2f

// workspace layout (float offsets)
constexpr int W_Q  = 0;         // 131072
constexpr int W_K  = 131072;    // 131072
constexpr int W_V  = 262144;    // 131072
constexpr int W_AO = 393216;    // 131072
constexpr int W_GA = 524288;    // 4096
constexpr int W_GR = 528384;    // 1048576 (g_rel -> logits)

// ---------------------------------------------------------------------------
template<int R, int PER>
__device__ __forceinline__ void stage_tile(const float* __restrict__ src, int ld,
                                           int row0, int k0, float* __restrict__ dst, int tid) {
    int row = tid / (16 / PER);
    int cb = (tid % (16 / PER)) * PER;
    const float* g = src + (size_t)(row0 + row) * ld + k0 + cb;
    float v[PER];
    #pragma unroll
    for (int u = 0; u < PER; ++u) v[u] = g[u];
    #pragma unroll
    for (int u = 0; u < PER; ++u) dst[(cb + u) * (R + 1) + row] = v[u];
}

__device__ __forceinline__ void gemm32(const float* __restrict__ A, const float* __restrict__ W,
                                       float* __restrict__ C, const float* __restrict__ bias,
                                       float sc, int m0, int n0, float* smem) {
    float* As = smem;
    float* Ws = smem + 16 * 33;
    int tid = threadIdx.x;
    int tx = tid & 15, ty = tid >> 4;
    float acc[2][2] = {};
    for (int k0 = 0; k0 < 256; k0 += 16) {
        stage_tile<32, 2>(A, 256, m0, k0, As, tid);
        stage_tile<32, 2>(W, 256, n0, k0, Ws, tid);
        __syncthreads();
        #pragma unroll
        for (int k = 0; k < 16; ++k) {
            float a0 = As[k * 33 + ty * 2], a1 = As[k * 33 + ty * 2 + 1];
            float w0 = Ws[k * 33 + tx * 2], w1 = Ws[k * 33 + tx * 2 + 1];
            acc[0][0] = fmaf(a0, w0, acc[0][0]);
            acc[0][1] = fmaf(a0, w1, acc[0][1]);
            acc[1][0] = fmaf(a1, w0, acc[1][0]);
            acc[1][1] = fmaf(a1, w1, acc[1][1]);
        }
        __syncthreads();
    }
    #pragma unroll
    for (int u = 0; u < 2; ++u)
        #pragma unroll
        for (int v = 0; v < 2; ++v) {
            float o = acc[u][v] * sc;
            if (bias) o += bias[n0 + tx * 2 + v];
            C[(size_t)(m0 + ty * 2 + u) * DMc + n0 + tx * 2 + v] = o;
        }
}

// ---------------------------------------------------------------------------
__device__ __forceinline__ void gemm_qkv_item(int w, const float* __restrict__ x,
        const float* __restrict__ WQ, const float* __restrict__ WK, const float* __restrict__ WV,
        float* __restrict__ ws, float* smem) {
    int z = w >> 7, r = w & 127;
    int m0 = (r >> 3) * 32, n0 = (r & 7) * 32;
    const float* W = (z == 0) ? WQ : (z == 1) ? WK : WV;
    float* C = ws + ((z == 0) ? W_Q : (z == 1) ? W_K : W_V);
    gemm32(x, W, C, nullptr, (z == 0) ? RSQRT_DH : 1.0f, m0, n0, smem);
}

__device__ __forceinline__ void gabs_item(int idx, const float* __restrict__ t,
        const float* __restrict__ mu_a, const float* __restrict__ sg_a,
        const float* __restrict__ w_a, float* __restrict__ ws, float* smem) {
    int tid = threadIdx.x;
    int h = idx & 7, b = (idx >> 3) & 1, q = idx >> 4;
    {
        float2 s2 = *(const float2*)(sg_a + h * 512 + tid * 2);
        float2 o;
        o.x = NEGC / (s2.x * s2.x);
        o.y = NEGC / (s2.y * s2.y);
        *(float2*)(smem + tid * 2) = o;
    }
    __syncthreads();
    int lane = tid & 63, tg = tid >> 6;
    int i = q * 64 + lane;
    float tv = t[(b * Lc + i) * 4 + tg];
    const float* muB = mu_a + h * 512 + tg * 4;
    const float* wB  = w_a  + h * 512 + tg * 4;
    const float* nsB = smem + tg * 4;
    float acc = 0.f;
    #pragma unroll 4
    for (int d = 0; d < 32; ++d) {
        float4 m4 = *(const float4*)(muB + d * 16);
        float4 w4 = *(const float4*)(wB  + d * 16);
        float4 n4 = *(const float4*)(nsB + d * 16);
        float d0 = tv - m4.x; acc = fmaf(w4.x, EXP2(d0 * d0 * n4.x), acc);
        float d1 = tv - m4.y; acc = fmaf(w4.y, EXP2(d1 * d1 * n4.y), acc);
        float d2 = tv - m4.z; acc = fmaf(w4.z, EXP2(d2 * d2 * n4.z), acc);
        float d3 = tv - m4.w; acc = fmaf(w4.w, EXP2(d3 * d3 * n4.w), acc);
    }
    float* red = smem + 544;   // 4x64
    red[tg * 64 + lane] = acc;
    __syncthreads();
    if (tid < 64)
        ws[W_GA + (b * Hc + h) * Lc + q * 64 + lane] =
            (red[lane] + red[64 + lane] + red[128 + lane] + red[192 + lane]) * (1.0f / 32.0f);
}

__device__ __forceinline__ void grel_ns2(const float* __restrict__ sg_r, int h, float* smem) {
    float2 s2 = *(const float2*)(sg_r + h * 512 + threadIdx.x * 2);
    float2 o;
    o.x = NEGC / (s2.x * s2.x);
    o.y = NEGC / (s2.y * s2.y);
    *(float2*)(smem + threadIdx.x * 2) = o;
}

// assumes ns2 already staged in smem[0..512); lt region at smem+544 (16x17)
__device__ __forceinline__ void grel_item(int idx, const float* __restrict__ t,
        const float* __restrict__ mu_r, const float* __restrict__ w_r,
        float* __restrict__ ws, float* smem) {
    int tid = threadIdx.x;
    int h = idx & 7, b = (idx >> 3) & 1, p = idx >> 4;
    int ti = 0;
    for (;; ++ti) { int c = 16 - ti; if (p < c) break; p -= c; }
    int tj = ti + p;
    int di = tid >> 4, dj = tid & 15;
    int i = ti * 16 + di, j = tj * 16 + dj;
    float4 t_i = *(const float4*)(t + (b * Lc + i) * 4);
    float4 t_j = *(const float4*)(t + (b * Lc + j) * 4);
    float tr[4] = {fabsf(t_i.x - t_j.x), fabsf(t_i.y - t_j.y),
                   fabsf(t_i.z - t_j.z), fabsf(t_i.w - t_j.w)};
    float a0 = 0.f, a1 = 0.f, a2 = 0.f, a3 = 0.f;
    #pragma unroll
    for (int tg = 0; tg < 4; ++tg) {
        const float* muB = mu_r + h * 512 + tg * 4;
        const float* wB  = w_r  + h * 512 + tg * 4;
        const float* nsB = smem + tg * 4;
        float tv = tr[tg];
        #pragma unroll 4
        for (int d = 0; d < 32; ++d) {
            float4 m4 = *(const float4*)(muB + d * 16);
            float4 w4 = *(const float4*)(wB  + d * 16);
            float4 n4 = *(const float4*)(nsB + d * 16);
            float d0 = tv - m4.x; a0 = fmaf(w4.x, EXP2(d0 * d0 * n4.x), a0);
            float d1 = tv - m4.y; a1 = fmaf(w4.y, EXP2(d1 * d1 * n4.y), a1);
            float d2 = tv - m4.z; a2 = fmaf(w4.z, EXP2(d2 * d2 * n4.z), a2);
            float d3 = tv - m4.w; a3 = fmaf(w4.w, EXP2(d3 * d3 * n4.w), a3);
        }
    }
    float g = ((a0 + a1) + (a2 + a3)) * (1.0f / 32.0f);
    float* gb = ws + W_GR + (size_t)(b * Hc + h) * (Lc * Lc);
    gb[i * Lc + j] = g;
    if (ti != tj) {
        float* lt = smem + 544;
        __syncthreads();
        lt[di * 17 + dj] = g;
        __syncthreads();
        gb[(tj * 16 + di) * Lc + (ti * 16 + dj)] = lt[dj * 17 + di];
    }
}

// ---------------------------------------------------------------------------
// sp_item: 32x32 logit tile. logit = S*(P*(2a*g_abs + b*g_rel)+g), in-place GR.
__device__ __forceinline__ void sp_item(int jt, int it, int bh,
        const float* __restrict__ x, const float* __restrict__ alpha,
        const float* __restrict__ beta, const float* __restrict__ gamma,
        float* __restrict__ ws, float* sm) {
    constexpr int PITCH = 33;
    int b = bh >> 3, h = bh & 7;
    int i0 = it * 32, j0 = jt * 32;
    int tid = threadIdx.x;
    float* sQ  = sm;
    float* sK  = sm + 32 * PITCH;
    float* sXi = sm + 64 * PITCH;
    float* sXj = sm + 96 * PITCH;
    const float* Q = ws + W_Q;
    const float* K = ws + W_K;
    {
        int r = tid >> 3, c4 = (tid & 7) * 4;
        float4 qv = *(const float4*)(Q + ((size_t)(b * Lc + i0 + r) * DMc + h * DHc + c4));
        float4 kv = *(const float4*)(K + ((size_t)(b * Lc + j0 + r) * DMc + h * DHc + c4));
        float4 xi = *(const float4*)(x + ((size_t)(b * Lc + i0 + r) * DMc + h * DHc + c4));
        float4 xj = *(const float4*)(x + ((size_t)(b * Lc + j0 + r) * DMc + h * DHc + c4));
        const float* q_ = (const float*)&qv; const float* k_ = (const float*)&kv;
        const float* a_ = (const float*)&xi; const float* c_ = (const float*)&xj;
        #pragma unroll
        for (int u = 0; u < 4; ++u) {
            sQ [(c4 + u) * PITCH + r] = q_[u];
            sK [(c4 + u) * PITCH + r] = k_[u];
            sXi[(c4 + u) * PITCH + r] = a_[u];
            sXj[(c4 + u) * PITCH + r] = c_[u];
        }
    }
    __syncthreads();
    int tx = tid & 15, ty = tid >> 4;
    int i2 = ty * 2, j2 = tx * 2;
    float accS[2][2] = {}, accP[2][2] = {};
    #pragma unroll 8
    for (int k = 0; k < 32; ++k) {
        float2 qa = *(const float2*)(sQ  + k * PITCH + i2);
        float2 kb = *(const float2*)(sK  + k * PITCH + j2);
        float2 xa = *(const float2*)(sXi + k * PITCH + i2);
        float2 xb = *(const float2*)(sXj + k * PITCH + j2);
        accS[0][0] = fmaf(qa.x, kb.x, accS[0][0]);
        accS[0][1] = fmaf(qa.x, kb.y, accS[0][1]);
        accS[1][0] = fmaf(qa.y, kb.x, accS[1][0]);
        accS[1][1] = fmaf(qa.y, kb.y, accS[1][1]);
        accP[0][0] = fmaf(xa.x, xb.x, accP[0][0]);
        accP[0][1] = fmaf(xa.x, xb.y, accP[0][1]);
        accP[1][0] = fmaf(xa.y, xb.x, accP[1][0]);
        accP[1][1] = fmaf(xa.y, xb.y, accP[1][1]);
    }
    float la = alpha[h], lb = beta[h], lg = gamma[h];
    float* gb = ws + W_GR + (size_t)bh * (Lc * Lc);
    const float* GA = ws + W_GA;
    #pragma unroll
    for (int u = 0; u < 2; ++u) {
        int i = i0 + i2 + u;
        float ca = 2.0f * la * GA[bh * Lc + i];
        float* addr = gb + (size_t)i * Lc + j0 + j2;
        float2 gr = *(const float2*)addr;
        float2 o;
        o.x = accS[u][0] * fmaf(accP[u][0], fmaf(lb, gr.x, ca), lg);
        o.y = accS[u][1] * fmaf(accP[u][1], fmaf(lb, gr.y, ca), lg);
        *(float2*)addr = o;
    }
}

// pv_item: softmax (full row) + PV for a 16-d half. sm usage: 8576 floats.
__device__ __forceinline__ void pv_item(int it, int bh, int half,
        float* __restrict__ ws, float* sm) {
    int b = bh >> 3, h = bh & 7;
    int i0 = it * 16;
    int tid = threadIdx.x;
    int ty = tid >> 4, tx = tid & 15;
    float* sP = sm;            // 16x264
    float* sV = sm + 4224;     // 256x17
    const float* GR = ws + W_GR;
    const float* V = ws + W_V;
    {
        const float* lrow = GR + (size_t)bh * (Lc * Lc) + (size_t)(i0 + ty) * Lc + tx * 16;
        float4 p0 = *(const float4*)(lrow);
        float4 p1 = *(const float4*)(lrow + 4);
        float4 p2 = *(const float4*)(lrow + 8);
        float4 p3 = *(const float4*)(lrow + 12);
        float m = fmaxf(fmaxf(fmaxf(p0.x, p0.y), fmaxf(p0.z, p0.w)),
                        fmaxf(fmaxf(p1.x, p1.y), fmaxf(p1.z, p1.w)));
        m = fmaxf(m, fmaxf(fmaxf(fmaxf(p2.x, p2.y), fmaxf(p2.z, p2.w)),
                           fmaxf(fmaxf(p3.x, p3.y), fmaxf(p3.z, p3.w))));
        #pragma unroll
        for (int s = 1; s < 16; s <<= 1) m = fmaxf(m, __shfl_xor(m, s, 64));
        float4 e0, e1, e2, e3;
        e0.x = EXP2((p0.x - m) * LOG2E); e0.y = EXP2((p0.y - m) * LOG2E);
        e0.z = EXP2((p0.z - m) * LOG2E); e0.w = EXP2((p0.w - m) * LOG2E);
        e1.x = EXP2((p1.x - m) * LOG2E); e1.y = EXP2((p1.y - m) * LOG2E);
        e1.z = EXP2((p1.z - m) * LOG2E); e1.w = EXP2((p1.w - m) * LOG2E);
        e2.x = EXP2((p2.x - m) * LOG2E); e2.y = EXP2((p2.y - m) * LOG2E);
        e2.z = EXP2((p2.z - m) * LOG2E); e2.w = EXP2((p2.w - m) * LOG2E);
        e3.x = EXP2((p3.x - m) * LOG2E); e3.y = EXP2((p3.y - m) * LOG2E);
        e3.z = EXP2((p3.z - m) * LOG2E); e3.w = EXP2((p3.w - m) * LOG2E);
        float sum = ((e0.x + e0.y) + (e0.z + e0.w)) + ((e1.x + e1.y) + (e1.z + e1.w)) +
                    ((e2.x + e2.y) + (e2.z + e2.w)) + ((e3.x + e3.y) + (e3.z + e3.w));
        #pragma unroll
        for (int s = 1; s < 16; s <<= 1) sum += __shfl_xor(sum, s, 64);
        float rs = 1.0f / sum;
        float* prow = sP + ty * 264 + tx * 16;
        e0.x *= rs; e0.y *= rs; e0.z *= rs; e0.w *= rs;
        e1.x *= rs; e1.y *= rs; e1.z *= rs; e1.w *= rs;
        e2.x *= rs; e2.y *= rs; e2.z *= rs; e2.w *= rs;
        e3.x *= rs; e3.y *= rs; e3.z *= rs; e3.w *= rs;
        *(float4*)(prow)      = e0;
        *(float4*)(prow + 4)  = e1;
        *(float4*)(prow + 8)  = e2;
        *(float4*)(prow + 12) = e3;
    }
    {
        int r = tid >> 2, c4 = (tid & 3) * 4;
        #pragma unroll
        for (int u = 0; u < 4; ++u) {
            int j = r + u * 64;
            float4 vv = *(const float4*)(V + ((size_t)(b * Lc + j) * DMc
                                              + h * DHc + half * 16 + c4));
            sV[j * 17 + c4 + 0] = vv.x;
            sV[j * 17 + c4 + 1] = vv.y;
            sV[j * 17 + c4 + 2] = vv.z;
            sV[j * 17 + c4 + 3] = vv.w;
        }
    }
    __syncthreads();
    {
        float a0 = 0.f, a1 = 0.f, a2 = 0.f, a3 = 0.f;
        #pragma unroll 4
        for (int j4 = 0; j4 < 256; j4 += 4) {
            float4 p4 = *(const float4*)(sP + ty * 264 + j4);
            a0 = fmaf(p4.x, sV[(j4 + 0) * 17 + tx], a0);
            a1 = fmaf(p4.y, sV[(j4 + 1) * 17 + tx], a1);
            a2 = fmaf(p4.z, sV[(j4 + 2) * 17 + tx], a2);
            a3 = fmaf(p4.w, sV[(j4 + 3) * 17 + tx], a3);
        }
        ws[W_AO + (size_t)(b * Lc + i0 + ty) * DMc + h * DHc + half * 16 + tx] =
            (a0 + a1) + (a2 + a3);
    }
}

// ===========================================================================
// kFused: ONE cooperative kernel, grid 1024 = 256 CU x 4 blocks (LDS 34.3KB).
//   Phase A: 2624 work items (QKV gemm / gabs / grel), 2-3 per block.
//            All grel items of a block share (b,h) -> ns2 staged once.
//   Phase B: sp (1024 items) | Phase C: pv (512) | Phase D: out gemm (128),
//   separated by cg grid syncs.
// ===========================================================================
__global__ void __launch_bounds__(256, 4) kFused(
    const float* __restrict__ x, const float* __restrict__ t,
    const float* __restrict__ WQ, const float* __restrict__ WK, const float* __restrict__ WV,
    const float* __restrict__ WO, const float* __restrict__ bO,
    const float* __restrict__ mu_a, const float* __restrict__ sg_a, const float* __restrict__ w_a,
    const float* __restrict__ mu_r, const float* __restrict__ sg_r, const float* __restrict__ w_r,
    const float* __restrict__ alpha, const float* __restrict__ beta, const float* __restrict__ gamma,
    float* __restrict__ ws, float* __restrict__ out)
{
    __shared__ float sm[8576];   // 34304 B
    cg::grid_group grid = cg::this_grid();
    int bx = blockIdx.x;

    // ---- Phase A ----
    {
        bool ns2_done = false;
        for (int w = bx; w < 2624; w += 1024) {
            if (w < 384) {
                gemm_qkv_item(w, x, WQ, WK, WV, ws, sm);
            } else if (w < 448) {
                gabs_item(w - 384, t, mu_a, sg_a, w_a, ws, sm);
            } else {
                if (!ns2_done) {
                    __syncthreads();
                    grel_ns2(sg_r, (w - 448) & 7, sm);
                    ns2_done = true;
                }
                __syncthreads();
                grel_item(w - 448, t, mu_r, w_r, ws, sm);
            }
        }
    }
    grid.sync();

    // ---- Phase B ----
    sp_item(bx & 7, (bx >> 3) & 7, bx >> 6, x, alpha, beta, gamma, ws, sm);
    grid.sync();

    // ---- Phase C ----
    if (bx < 512)
        pv_item(bx & 15, (bx >> 4) & 15, bx >> 8, ws, sm);
    grid.sync();

    // ---- Phase D ----
    if (bx < 128)
        gemm32(ws + W_AO, WO, out, bO, 1.0f, (bx & 15) * 32, (bx >> 4) * 32, sm);
}

// ===========================================================================
// Fallback path (non-cooperative): proven R7 structure.
// ===========================================================================
__global__ void __launch_bounds__(256) kA(
    const float* __restrict__ x, const float* __restrict__ t,
    const float* __restrict__ WQ, const float* __restrict__ WK, const float* __restrict__ WV,
    const float* __restrict__ mu_a, const float* __restrict__ sg_a, const float* __restrict__ w_a,
    const float* __restrict__ mu_r, const float* __restrict__ sg_r, const float* __restrict__ w_r,
    float* __restrict__ ws)
{
    __shared__ float sm[1088];
    int bx = blockIdx.x;
    if (bx < 384) {
        gemm_qkv_item(bx, x, WQ, WK, WV, ws, sm);
    } else if (bx < 448) {
        gabs_item(bx - 384, t, mu_a, sg_a, w_a, ws, sm);
    } else {
        grel_ns2(sg_r, (bx - 448) & 7, sm);
        __syncthreads();
        grel_item(bx - 448, t, mu_r, w_r, ws, sm);
    }
}

__global__ void __launch_bounds__(256) kSP(
    const float* __restrict__ x, const float* __restrict__ alpha,
    const float* __restrict__ beta, const float* __restrict__ gamma,
    float* __restrict__ ws)
{
    __shared__ float sm[4224];
    sp_item(blockIdx.x, blockIdx.y, blockIdx.z, x, alpha, beta, gamma, ws, sm);
}

__global__ void __launch_bounds__(256) kPV(float* __restrict__ ws) {
    __shared__ float sm[8576];
    pv_item(blockIdx.x, blockIdx.y, blockIdx.z, ws, sm);
}

__global__ void __launch_bounds__(256) kOut(const float* __restrict__ ws_c,
                                            const float* __restrict__ WO,
                                            const float* __restrict__ bO,
                                            float* __restrict__ out) {
    __shared__ float sm[2 * 16 * 33];
    gemm32(ws_c + W_AO, WO, out, bO, 1.0f, blockIdx.x * 32, blockIdx.y * 32, sm);
}

// ===========================================================================
extern "C" void kernel_launch(void* const* d_in, const int* in_sizes, int n_in,
                              void* d_out, int out_size, void* d_ws, size_t ws_size,
                              hipStream_t stream) {
    (void)in_sizes; (void)n_in; (void)out_size; (void)ws_size;
    const float* x      = (const float*)d_in[0];
    const float* t      = (const float*)d_in[1];
    const float* WQ     = (const float*)d_in[2];
    const float* WK     = (const float*)d_in[3];
    const float* WV     = (const float*)d_in[4];
    const float* WO     = (const float*)d_in[5];
    const float* bO     = (const float*)d_in[6];
    const float* mu_abs = (const float*)d_in[7];
    const float* sg_abs = (const float*)d_in[8];
    const float* w_abs  = (const float*)d_in[9];
    const float* mu_rel = (const float*)d_in[10];
    const float* sg_rel = (const float*)d_in[11];
    const float* w_rel  = (const float*)d_in[12];
    const float* alpha  = (const float*)d_in[13];
    const float* beta   = (const float*)d_in[14];
    const float* gamma  = (const float*)d_in[15];
    float* out = (float*)d_out;
    float* ws = (float*)d_ws;

    void* args[] = {(void*)&x, (void*)&t, (void*)&WQ, (void*)&WK, (void*)&WV,
                    (void*)&WO, (void*)&bO,
                    (void*)&mu_abs, (void*)&sg_abs, (void*)&w_abs,
                    (void*)&mu_rel, (void*)&sg_rel, (void*)&w_rel,
                    (void*)&alpha, (void*)&beta, (void*)&gamma,
                    (void*)&ws, (void*)&out};
    hipError_t e = hipLaunchCooperativeKernel((const void*)kFused, dim3(1024), dim3(256),
                                              args, 0, stream);
    if (e != hipSuccess) {
        (void)hipGetLastError();   // clear sticky error; use proven 4-kernel path
        kA<<<dim3(2624), dim3(256), 0, stream>>>(x, t, WQ, WK, WV,
                                                 mu_abs, sg_abs, w_abs,
                                                 mu_rel, sg_rel, w_rel, ws);
        kSP<<<dim3(8, 8, 16), dim3(256), 0, stream>>>(x, alpha, beta, gamma, ws);
        kPV<<<dim3(16, 16, 2), dim3(256), 0, stream>>>(ws);
        kOut<<<dim3(16, 8), dim3(256), 0, stream>>>(ws, WO, bO, out);
    }
}